// Round 5
// baseline (224.918 us; speedup 1.0000x reference)
//
#include <hip/hip_runtime.h>

// GatherFromIndices: out[b,n,k,:] = k<K ? (inds[b,n,k]>=0 ? inp[b, inds[b,n,k]%N, :] : 0)
//                                  : inp[b,n,:]   (self slot, k==K)
// inp [B,N,F] f32, inds [B,N,K] i32, out [B,N,K+1,F] f32.
//
// Key idea: batch b's gather working set (N*F*4 = 2.56 MB) fits one XCD's
// 4 MiB L2. Blocks round-robin across the 8 XCDs by blockIdx%8, so we pin
// batch b to XCD b -> gathers are L2 hits. Output stores are non-temporal
// (write-once stream) so they don't evict the table.

typedef float f32x4 __attribute__((ext_vector_type(4)));  // clang-native vec,
                                                          // valid for nontemporal builtins

constexpr int B    = 8;
constexpr int N    = 10000;
constexpr int F    = 64;      // 16 f32x4 per row
constexpr int K    = 8;
constexpr int KP1  = K + 1;
constexpr int ROWS_PER_BATCH  = N * KP1;                      // 90000
constexpr int ROWS_PER_BLOCK  = 16;                           // 256 thr / 16 lanes-per-row
constexpr int BLOCKS_PER_BATCH = ROWS_PER_BATCH / ROWS_PER_BLOCK; // 5625
constexpr int NBLOCKS = BLOCKS_PER_BATCH * B;                 // 45000

__global__ __launch_bounds__(256)
void GatherFromIndices_kernel(const float* __restrict__ inp,
                              const int*   __restrict__ inds,
                              float*       __restrict__ out) {
    int b     = blockIdx.x & 7;    // XCD-pinned batch (blocks round-robin XCDs)
    int chunk = blockIdx.x >> 3;   // 0..5624 within the batch
    int t     = threadIdx.x;
    int lr    = t >> 4;            // local row within block's 16-row chunk
    int lane  = t & 15;            // f32x4 slot within the 64-float row

    int row_in_batch = chunk * ROWS_PER_BLOCK + lr;  // 0..89999
    int n  = row_in_batch / KP1;
    int k  = row_in_batch - n * KP1;                 // neighbor slot (K == self)
    int bn = b * N + n;

    f32x4 v;
    if (k == K) {
        v = ((const f32x4*)(inp + (size_t)bn * F))[lane];            // self row
    } else {
        int idx = inds[bn * K + k];
        if (idx < 0) {
            v = (f32x4){0.f, 0.f, 0.f, 0.f};                         // MASK_VALUE
        } else {
            int row = b * N + (idx % N);     // faithful to (idx % N) + seq offset
            v = ((const f32x4*)(inp + (size_t)row * F))[lane];
        }
    }
    size_t r = (size_t)b * ROWS_PER_BATCH + row_in_batch;
    __builtin_nontemporal_store(v, ((f32x4*)out) + r * 16 + lane);
}

extern "C" void kernel_launch(void* const* d_in, const int* in_sizes, int n_in,
                              void* d_out, int out_size, void* d_ws, size_t ws_size,
                              hipStream_t stream) {
    const float* inp  = (const float*)d_in[0];
    const int*   inds = (const int*)d_in[1];
    float*       out  = (float*)d_out;

    GatherFromIndices_kernel<<<NBLOCKS, 256, 0, stream>>>(inp, inds, out);
}

// Round 8
// 209.531 us; speedup vs baseline: 1.0734x; 1.0734x over previous
//
#include <hip/hip_runtime.h>

// GatherFromIndices: out[b,n,k,:] = k<K ? (inds[b,n,k]>=0 ? inp[b, inds[b,n,k]%N, :] : 0)
//                                  : inp[b,n,:]   (self slot, k==K)
// inp [B,N,F] f32, inds [B,N,K] i32, out [B,N,K+1,F] f32.
//
// Structure: latency amortization. Output rows 0..89999 are batch 0, so
// row = b*90000 + rg. One thread owns slot (n,k) for ALL 8 batches:
//   8 independent idx loads -> 8 independent row gathers -> 8 stores.
// Two dependency levels, 8-wide MLP each, vs the 1-wide chain of round 5.
// Self slot (k==K) handled branchlessly via idx = n.
//
// NOTE: plain (coherent) stores, NOT __builtin_nontemporal_store. NT stores
// raced with the harness's 0xAA poison memset (dirty L2 lines evicting over
// NT data in HBM) -> nondeterministic post-timing divergence in round 7.

typedef float f32x4 __attribute__((ext_vector_type(4)));

constexpr int B    = 8;
constexpr int N    = 10000;
constexpr int F    = 64;      // 16 f32x4 per row
constexpr int K    = 8;
constexpr int KP1  = K + 1;
constexpr int ROWS_PER_BATCH = N * KP1;            // 90000
constexpr int NTHREADS = ROWS_PER_BATCH * 16;      // 16 lanes per row
constexpr int NBLOCKS  = NTHREADS / 256;           // 5625, exact

__global__ __launch_bounds__(256)
void GatherFromIndices_kernel(const float* __restrict__ inp,
                              const int*   __restrict__ inds,
                              float*       __restrict__ out) {
    int t    = blockIdx.x * 256 + threadIdx.x;
    int rg   = t >> 4;        // row-within-batch in [0, 90000)
    int lane = t & 15;        // f32x4 slot within the 64-float row

    int n  = rg / KP1;        // node index
    int kk = rg - n * KP1;    // neighbor slot, K == self
    bool self  = (kk == K);
    int  kload = self ? 0 : kk;   // clamped so the inds load is always in-bounds

    // Level 1: 8 independent index loads (one per batch).
    int idx[B];
#pragma unroll
    for (int b = 0; b < B; ++b) {
        int iv = inds[(b * N + n) * K + kload];
        idx[b] = self ? n : iv;       // self slot gathers its own row
    }

    // Level 2: 8 independent 16 B row-fragment gathers (branchless mask).
    f32x4 v[B];
#pragma unroll
    for (int b = 0; b < B; ++b) {
        int  iv  = idx[b];
        int  m   = iv % N;                       // identity for valid entries
        int  row = (iv < 0) ? 0 : (b * N + m);   // safe row when masked
        f32x4 ld = ((const f32x4*)(inp + (size_t)row * F))[lane];
        v[b] = (iv < 0) ? (f32x4)(0.f) : ld;     // MASK_VALUE = 0
    }

    // Level 3: 8 coherent stores; per wave each is 1 KB contiguous.
#pragma unroll
    for (int b = 0; b < B; ++b) {
        size_t r = (size_t)b * ROWS_PER_BATCH + rg;
        ((f32x4*)out)[r * 16 + lane] = v[b];
    }
}

extern "C" void kernel_launch(void* const* d_in, const int* in_sizes, int n_in,
                              void* d_out, int out_size, void* d_ws, size_t ws_size,
                              hipStream_t stream) {
    const float* inp  = (const float*)d_in[0];
    const int*   inds = (const int*)d_in[1];
    float*       out  = (float*)d_out;

    GatherFromIndices_kernel<<<NBLOCKS, 256, 0, stream>>>(inp, inds, out);
}

// Round 9
// 206.480 us; speedup vs baseline: 1.0893x; 1.0148x over previous
//
#include <hip/hip_runtime.h>

// GatherFromIndices: out[b,n,k,:] = k<K ? (inds[b,n,k]>=0 ? inp[b, inds[b,n,k]%N, :] : 0)
//                                  : inp[b,n,:]   (self slot, k==K)
// inp [B,N,F] f32, inds [B,N,K] i32, out [B,N,K+1,F] f32.
//
// Round-9 structure: one 16-lane group owns node (b,n) and emits all 9 output
// rows (9 x 256 B contiguous). Index row inds[b,n,0:8] comes in as two
// broadcast int4 loads (one cache line). Masked slots use a real `if` so the
// exec-masked gather issues no memory traffic. XCD pin: b = blockIdx&7 ->
// batch b's 2.56 MB table slice lives in XCD b's 4 MiB L2.
// Plain coherent stores (NT stores raced with the harness poison fill, R7).

typedef float f32x4 __attribute__((ext_vector_type(4)));
typedef int   i32x4 __attribute__((ext_vector_type(4)));

constexpr int B   = 8;
constexpr int N   = 10000;
constexpr int F   = 64;       // 16 f32x4 per row
constexpr int K   = 8;
constexpr int KP1 = K + 1;
constexpr int GROUPS_PER_BLOCK = 16;                    // 256 thr / 16 lanes
constexpr int BLOCKS_PER_BATCH = N / GROUPS_PER_BLOCK;  // 625
constexpr int NBLOCKS = BLOCKS_PER_BATCH * B;           // 5000 (≡0 mod 8)

__global__ __launch_bounds__(256)
void GatherFromIndices_kernel(const float* __restrict__ inp,
                              const int*   __restrict__ inds,
                              float*       __restrict__ out) {
    int b    = blockIdx.x & 7;        // XCD-pinned batch
    int slot = blockIdx.x >> 3;       // 0..624 within batch
    int g    = threadIdx.x >> 4;      // group 0..15
    int lane = threadIdx.x & 15;      // f32x4 slot within 64-float row

    int n  = slot * GROUPS_PER_BLOCK + g;   // 0..9999
    int bn = b * N + n;

    // One cache line of indices, broadcast across the 16-lane group.
    const i32x4* ip = (const i32x4*)(inds + (size_t)bn * K);
    i32x4 i0 = ip[0];
    i32x4 i1 = ip[1];

    const f32x4* table = (const f32x4*)inp;
    f32x4* outp = (f32x4*)out + (size_t)bn * (KP1 * 16) + lane;

#pragma unroll
    for (int k = 0; k < K; ++k) {
        int iv = (k < 4) ? i0[k] : i1[k - 4];   // compile-time component select
        f32x4 v = (f32x4){0.f, 0.f, 0.f, 0.f};  // MASK_VALUE row
        if (iv >= 0) {                           // exec-masked: masked groups skip the load
            int row = b * N + (iv % N);          // faithful to (idx % N) + seq offset
            v = table[(size_t)row * 16 + lane];
        }
        outp[k * 16] = v;
    }
    // self slot k == K: group's own row; across the block this is 4 KB contiguous
    outp[K * 16] = table[(size_t)bn * 16 + lane];
}

extern "C" void kernel_launch(void* const* d_in, const int* in_sizes, int n_in,
                              void* d_out, int out_size, void* d_ws, size_t ws_size,
                              hipStream_t stream) {
    const float* inp  = (const float*)d_in[0];
    const int*   inds = (const int*)d_in[1];
    float*       out  = (float*)d_out;

    GatherFromIndices_kernel<<<NBLOCKS, 256, 0, stream>>>(inp, inds, out);
}